// Round 1
// baseline (2118.535 us; speedup 1.0000x reference)
//
#include <hip/hip_runtime.h>
#include <math.h>

// ---------------------------------------------------------------------------
// BMN forward on MI355X. Shapes (fixed): B=2, T=100, DM=100, NS=32, NSPB=3,
// FEAT=400, H1=256, H2=128, H3=512.
// Key refactor: sample_mask is s-shift-invariant => 100x96 (floor,frac) table;
// einsum contraction reordered so the big mask matmul becomes
//   q[b,o,n,pos] = sum_c w3d[o,c,n] p[b,c,pos]   (small GEMM)
//   fmap[b,o,d,s] = relu(b3d[o] + valid(d,s)/3 * sum_k interp(q, table))
// ---------------------------------------------------------------------------

__global__ void build_table_k(int* __restrict__ fl, float* __restrict__ fr) {
  int idx = blockIdx.x * blockDim.x + threadIdx.x;
  if (idx >= 9600) return;
  int d = idx / 96, k = idx % 96;
  double center = (double)d + 1.0;
  double plen = (double)d + 2.0 * 0.5 * center;   // = 2d+1
  double step = plen / 95.0;
  double off = -center * 0.5 + (double)k * step;
  double fld = floor(off);
  fl[idx] = (int)fld;
  fr[idx] = (float)(off - fld);
}

// generic k=3 pad=1 grouped conv1d + relu. grid.x = B*Cout, block = 128 (t)
__global__ void conv1d_k3(const float* __restrict__ in, const float* __restrict__ wt,
                          const float* __restrict__ bias, float* __restrict__ out,
                          int Cin_total, int Cin_g, int Cout, int ocpg) {
  int bo = blockIdx.x;
  int o = bo % Cout;
  int b = bo / Cout;
  int g = o / ocpg;
  int t = threadIdx.x;
  if (t >= 100) return;
  const float* ib = in + ((size_t)b * Cin_total + (size_t)g * Cin_g) * 100;
  const float* wr = wt + (size_t)o * Cin_g * 3;
  float acc = bias[o];
  for (int c = 0; c < Cin_g; ++c) {
    const float* row = ib + (size_t)c * 100;
    float w0 = wr[c * 3 + 0], w1 = wr[c * 3 + 1], w2 = wr[c * 3 + 2];
    float a = (t > 0) ? row[t - 1] : 0.f;
    float m = row[t];
    float z = (t < 99) ? row[t + 1] : 0.f;
    acc += w0 * a + w1 * m + w2 * z;
  }
  out[(size_t)bo * 100 + t] = fmaxf(acc, 0.f);
}

// 1x1 conv to 1 channel + sigmoid. 200 outputs.
__global__ void head_sig(const float* __restrict__ mid, const float* __restrict__ w,
                         const float* __restrict__ bias, float* __restrict__ out) {
  int idx = blockIdx.x * blockDim.x + threadIdx.x;
  if (idx >= 200) return;
  int b = idx / 100, t = idx % 100;
  float acc = bias[0];
  for (int c = 0; c < 256; ++c)
    acc += mid[((size_t)b * 256 + c) * 100 + t] * w[c];
  out[idx] = 1.f / (1.f + expf(-acc));
}

// q[b,o,n,pos] = sum_c w3d[o,c,n] * p[b,c,pos].  grid.x = B*512*32, block 128
__global__ void qgemm_k(const float* __restrict__ p, const float* __restrict__ w3d,
                        float* __restrict__ q) {
  int id = blockIdx.x;
  int n = id & 31;
  int o = (id >> 5) & 511;
  int b = id >> 14;
  int pos = threadIdx.x;
  if (pos >= 100) return;
  const float* pb = p + (size_t)b * 25600 + pos;
  const float* wr = w3d + (size_t)o * 8192 + n;
  float acc = 0.f;
#pragma unroll 8
  for (int c = 0; c < 256; ++c)
    acc += pb[(size_t)c * 100] * wr[(size_t)c * 32];
  q[(size_t)id * 100 + pos] = acc;
}

// fmap[b,o,d,s] via table-driven sparse interp of q rows staged in LDS.
// grid = (1024, 10); block 128 (s). Each block: one (b,o), 10 d values.
__global__ void fmap_k(const float* __restrict__ q, const int* __restrict__ tfl,
                       const float* __restrict__ tfr, const float* __restrict__ b3d,
                       float* __restrict__ out) {
  __shared__ float qs[3200];
  __shared__ int fls[96];
  __shared__ float frs[96];
  int bo = blockIdx.x;
  int o = bo & 511;
  const float* qb = q + (size_t)bo * 3200;
  for (int i = threadIdx.x; i < 3200; i += 128) qs[i] = qb[i];
  float bias = b3d[o];
  int s = threadIdx.x;
  for (int dd = 0; dd < 10; ++dd) {
    int d = blockIdx.y * 10 + dd;
    __syncthreads();  // protects qs (first iter) and fls/frs (later iters)
    if (threadIdx.x < 96) {
      fls[threadIdx.x] = tfl[d * 96 + threadIdx.x];
      frs[threadIdx.x] = tfr[d * 96 + threadIdx.x];
    }
    __syncthreads();
    if (s < 100) {
      float acc = 0.f;
#pragma unroll
      for (int k = 0; k < 96; ++k) {
        int i = s + fls[k];
        float fr = frs[k];
        float w0 = ((unsigned)i <= 99u) ? (1.f - fr) : 0.f;
        float w1 = ((unsigned)(i + 1) <= 99u) ? fr : 0.f;
        // samp in (-1,0): trunc-based reference nets 1.0 at pos 0
        if (i == -1) w1 = (fr > 0.f) ? 1.f : 0.f;
        int i0 = i < 0 ? 0 : (i > 99 ? 99 : i);
        int i1 = (i + 1) < 0 ? 0 : ((i + 1) > 99 ? 99 : (i + 1));
        int nb = (k / 3) * 100;
        acc += w0 * qs[nb + i0] + w1 * qs[nb + i1];
      }
      float pre = bias + ((s + d < 100) ? acc * (1.f / 3.f) : 0.f);
      out[((size_t)bo * 100 + d) * 100 + s] = fmaxf(pre, 0.f);
    }
  }
}

// 1x1 conv 512->128 + relu. grid=(200,4) [bd, octile], block=128 (x)
__global__ void conv1x1_c1(const float* __restrict__ in, const float* __restrict__ w,
                           const float* __restrict__ bias, float* __restrict__ out) {
  __shared__ float wl[32 * 128];  // [oc_local][c_local]
  int bd = blockIdx.x;
  int y = bd % 100;
  int b = bd / 100;
  int oc0 = blockIdx.y * 32;
  int t = threadIdx.x;
  float acc[32];
#pragma unroll
  for (int j = 0; j < 32; ++j) acc[j] = 0.f;
  const float* inb = in + (size_t)b * 512 * 10000 + (size_t)y * 100;
  for (int cbase = 0; cbase < 512; cbase += 128) {
    __syncthreads();
#pragma unroll
    for (int r = 0; r < 32; ++r)
      wl[r * 128 + t] = w[(size_t)(oc0 + r) * 512 + cbase + t];
    __syncthreads();
    if (t < 100) {
      for (int c = 0; c < 128; c += 4) {
        float v0 = inb[(size_t)(cbase + c + 0) * 10000 + t];
        float v1 = inb[(size_t)(cbase + c + 1) * 10000 + t];
        float v2 = inb[(size_t)(cbase + c + 2) * 10000 + t];
        float v3 = inb[(size_t)(cbase + c + 3) * 10000 + t];
#pragma unroll
        for (int j = 0; j < 32; ++j) {
          const float4 w4 = *(const float4*)&wl[j * 128 + c];  // uniform broadcast
          acc[j] += w4.x * v0 + w4.y * v1 + w4.z * v2 + w4.w * v3;
        }
      }
    }
  }
  if (t < 100) {
#pragma unroll
    for (int j = 0; j < 32; ++j)
      out[((size_t)(b * 128 + oc0 + j) * 100 + y) * 100 + t] =
          fmaxf(acc[j] + bias[oc0 + j], 0.f);
  }
}

// 3x3 conv 128->128 pad 1 + relu. grid=(200,4), block=128
__global__ void conv3x3_c(const float* __restrict__ in, const float* __restrict__ w,
                          const float* __restrict__ bias, float* __restrict__ out) {
  __shared__ float wl[16 * 9 * 32];  // [c_local][tap][oc_local]
  int bd = blockIdx.x;
  int y = bd % 100;
  int b = bd / 100;
  int oc0 = blockIdx.y * 32;
  int t = threadIdx.x;
  float acc[32];
#pragma unroll
  for (int j = 0; j < 32; ++j) acc[j] = 0.f;
  for (int cbase = 0; cbase < 128; cbase += 16) {
    __syncthreads();
    for (int idx = t; idx < 16 * 9 * 32; idx += 128) {
      int j = idx & 31;
      int tap = (idx >> 5) % 9;
      int c = idx / 288;
      wl[idx] = w[((size_t)(oc0 + j) * 128 + cbase + c) * 9 + tap];
    }
    __syncthreads();
    if (t < 100) {
      for (int c = 0; c < 16; ++c) {
        const float* ib = in + ((size_t)b * 128 + cbase + c) * 10000;
#pragma unroll
        for (int ky = 0; ky < 3; ++ky) {
          int yy = y + ky - 1;
          if ((unsigned)yy > 99u) continue;
          const float* row = ib + (size_t)yy * 100;
          float vm = (t > 0) ? row[t - 1] : 0.f;
          float v0 = row[t];
          float vp = (t < 99) ? row[t + 1] : 0.f;
          const float* wt = &wl[(c * 9 + ky * 3) * 32];
#pragma unroll
          for (int j4 = 0; j4 < 32; j4 += 4) {
            float4 wa = *(const float4*)&wt[j4];        // kx=0 -> x-1
            float4 wb = *(const float4*)&wt[32 + j4];   // kx=1 -> x
            float4 wc = *(const float4*)&wt[64 + j4];   // kx=2 -> x+1
            acc[j4 + 0] += wa.x * vm + wb.x * v0 + wc.x * vp;
            acc[j4 + 1] += wa.y * vm + wb.y * v0 + wc.y * vp;
            acc[j4 + 2] += wa.z * vm + wb.z * v0 + wc.z * vp;
            acc[j4 + 3] += wa.w * vm + wb.w * v0 + wc.w * vp;
          }
        }
      }
    }
  }
  if (t < 100) {
#pragma unroll
    for (int j = 0; j < 32; ++j)
      out[((size_t)(b * 128 + oc0 + j) * 100 + y) * 100 + t] =
          fmaxf(acc[j] + bias[oc0 + j], 0.f);
  }
}

// final 1x1 conv 128->2 + sigmoid -> conf
__global__ void conv1x1_final(const float* __restrict__ in, const float* __restrict__ w,
                              const float* __restrict__ bias, float* __restrict__ out) {
  int idx = blockIdx.x * blockDim.x + threadIdx.x;
  if (idx >= 40000) return;
  int sp = idx % 10000;
  int i = (idx / 10000) & 1;
  int b = idx / 20000;
  float acc = bias[i];
  const float* ib = in + (size_t)b * 128 * 10000 + sp;
#pragma unroll 4
  for (int c = 0; c < 128; ++c)
    acc += ib[(size_t)c * 10000] * w[i * 128 + c];
  out[idx] = 1.f / (1.f + expf(-acc));
}

extern "C" void kernel_launch(void* const* d_in, const int* in_sizes, int n_in,
                              void* d_out, int out_size, void* d_ws, size_t ws_size,
                              hipStream_t stream) {
  const float* x    = (const float*)d_in[0];
  const float* w_b1 = (const float*)d_in[1];
  const float* b_b1 = (const float*)d_in[2];
  const float* w_b2 = (const float*)d_in[3];
  const float* b_b2 = (const float*)d_in[4];
  const float* w_s1 = (const float*)d_in[5];
  const float* b_s1 = (const float*)d_in[6];
  const float* w_s2 = (const float*)d_in[7];
  const float* b_s2 = (const float*)d_in[8];
  const float* w_e1 = (const float*)d_in[9];
  const float* b_e1 = (const float*)d_in[10];
  const float* w_e2 = (const float*)d_in[11];
  const float* b_e2 = (const float*)d_in[12];
  const float* w_p  = (const float*)d_in[13];
  const float* b_p  = (const float*)d_in[14];
  const float* w_3d = (const float*)d_in[15];
  const float* b_3d = (const float*)d_in[16];
  const float* w_c1 = (const float*)d_in[17];
  const float* b_c1 = (const float*)d_in[18];
  const float* w_c2 = (const float*)d_in[19];
  const float* b_c2 = (const float*)d_in[20];
  const float* w_c3 = (const float*)d_in[21];
  const float* b_c3 = (const float*)d_in[22];
  const float* w_c4 = (const float*)d_in[23];
  const float* b_c4 = (const float*)d_in[24];
  // d_in[25] = sample_mask (unused: replaced by analytic table)

  float* out = (float*)d_out;
  float* ws  = (float*)d_ws;

  // workspace layout (floats)
  float* h1  = ws;                    // 51200
  float* h2  = ws + 51200;            // 51200
  float* mid = ws + 102400;           // 51200
  float* p   = ws + 153600;           // 51200
  float* q   = ws + 204800;           // 3,276,800
  float* c1b = ws + 3481600;          // 2,560,000
  float* c2b = ws + 6041600;          // 2,560,000
  int*   tfl = (int*)(ws + 8601600);  // 9600
  float* tfr = ws + 8611200;          // 9600

  float* out_conf  = out;             // 40,000
  float* out_start = out + 40000;     // 200
  float* out_end   = out + 40200;     // 200
  float* out_fmap  = out + 40400;     // 10,240,000

  hipLaunchKernelGGL(build_table_k, dim3(38), dim3(256), 0, stream, tfl, tfr);

  hipLaunchKernelGGL(conv1d_k3, dim3(512), dim3(128), 0, stream,
                     x, w_b1, b_b1, h1, 400, 100, 256, 64);
  hipLaunchKernelGGL(conv1d_k3, dim3(512), dim3(128), 0, stream,
                     h1, w_b2, b_b2, h2, 256, 64, 256, 64);

  hipLaunchKernelGGL(conv1d_k3, dim3(512), dim3(128), 0, stream,
                     h2, w_s1, b_s1, mid, 256, 64, 256, 64);
  hipLaunchKernelGGL(head_sig, dim3(2), dim3(128), 0, stream,
                     mid, w_s2, b_s2, out_start);
  hipLaunchKernelGGL(conv1d_k3, dim3(512), dim3(128), 0, stream,
                     h2, w_e1, b_e1, mid, 256, 64, 256, 64);
  hipLaunchKernelGGL(head_sig, dim3(2), dim3(128), 0, stream,
                     mid, w_e2, b_e2, out_end);

  hipLaunchKernelGGL(conv1d_k3, dim3(512), dim3(128), 0, stream,
                     h2, w_p, b_p, p, 256, 256, 256, 256);

  hipLaunchKernelGGL(qgemm_k, dim3(32768), dim3(128), 0, stream, p, w_3d, q);

  hipLaunchKernelGGL(fmap_k, dim3(1024, 10), dim3(128), 0, stream,
                     q, tfl, tfr, b_3d, out_fmap);

  hipLaunchKernelGGL(conv1x1_c1, dim3(200, 4), dim3(128), 0, stream,
                     out_fmap, w_c1, b_c1, c1b);
  hipLaunchKernelGGL(conv3x3_c, dim3(200, 4), dim3(128), 0, stream,
                     c1b, w_c2, b_c2, c2b);
  hipLaunchKernelGGL(conv3x3_c, dim3(200, 4), dim3(128), 0, stream,
                     c2b, w_c3, b_c3, c1b);
  hipLaunchKernelGGL(conv1x1_final, dim3(157), dim3(256), 0, stream,
                     c1b, w_c4, b_c4, out_conf);
}

// Round 2
// 1544.118 us; speedup vs baseline: 1.3720x; 1.3720x over previous
//
#include <hip/hip_runtime.h>
#include <math.h>

// ---------------------------------------------------------------------------
// BMN forward on MI355X. B=2, T=100, DM=100, NS=32, NSPB=3, FEAT=400,
// H1=256, H2=128, H3=512.
// fmap path: sample_mask is s-shift-invariant => per-d table of (ofs,w0,w1);
// interp runs on zero-padded LDS rows (PADW=252) so no bounds logic in the
// hot loop; negative-floor entries take a short slow path preserving the
// exact trunc/floor boundary semantics of the numpy reference.
// ---------------------------------------------------------------------------

#define PADW 252

__global__ void build_table_k(int* __restrict__ tofs, float* __restrict__ tw0,
                              float* __restrict__ tw1, int* __restrict__ nbase,
                              int* __restrict__ nfl, float* __restrict__ nw0,
                              float* __restrict__ nw1, float* __restrict__ nwn,
                              int* __restrict__ npos, int* __restrict__ nneg) {
  int d = blockIdx.x * blockDim.x + threadIdx.x;
  if (d >= 100) return;
  double center = (double)d + 1.0;
  double plen = (double)d + 2.0 * 0.5 * center;  // 2d+1
  double step = plen / 95.0;
  double xmin0 = -(center * 0.5);
  int pp = 0, qq = 0;
  for (int k = 0; k < 96; ++k) {
    double off = xmin0 + (double)k * step;
    double fld = floor(off);
    int fl = (int)fld;
    double frd = off - fld;
    float fr = (float)frd;
    int n = k / 3;
    float w0 = (1.0f - fr) * (1.0f / 3.0f);
    float w1 = fr * (1.0f / 3.0f);
    if (fl >= 0) {
      tofs[d * 96 + pp] = n * PADW + fl;
      tw0[d * 96 + pp] = w0;
      tw1[d * 96 + pp] = w1;
      ++pp;
    } else {
      nbase[d * 64 + qq] = n * PADW;
      nfl[d * 64 + qq] = fl;
      nw0[d * 64 + qq] = w0;
      nw1[d * 64 + qq] = w1;
      nwn[d * 64 + qq] = (frd > 0.0) ? (1.0f / 3.0f) : 0.0f;
      ++qq;
    }
  }
  while (pp & 3) { tofs[d*96+pp] = 0; tw0[d*96+pp] = 0.f; tw1[d*96+pp] = 0.f; ++pp; }
  while (qq & 3) { nbase[d*64+qq] = 0; nfl[d*64+qq] = 0; nw0[d*64+qq] = 0.f;
                   nw1[d*64+qq] = 0.f; nwn[d*64+qq] = 0.f; ++qq; }
  npos[d] = pp;
  nneg[d] = qq;
}

// transpose conv2d weights for SGPR (scalar-load) access
__global__ void prep_w_k(const float* __restrict__ w_c1, const float* __restrict__ w_c2,
                         const float* __restrict__ w_c3, float* __restrict__ wT1,
                         float* __restrict__ wT2, float* __restrict__ wT3) {
  int idx = blockIdx.x * 256 + threadIdx.x;
  if (idx < 512 * 128) {  // wT1[c*128+oc] = w_c1[oc*512+c]
    int c = idx >> 7, oc = idx & 127;
    wT1[idx] = w_c1[oc * 512 + c];
  }
  if (idx < 128 * 9 * 128) {  // wT[(c*9+tap)*128+oc] = w[(oc*128+c)*9+tap]
    int oc = idx & 127;
    int r = idx >> 7;
    int c = r / 9, tap = r % 9;
    wT2[idx] = w_c2[(oc * 128 + c) * 9 + tap];
    wT3[idx] = w_c3[(oc * 128 + c) * 9 + tap];
  }
}

// generic k=3 pad=1 grouped conv1d + relu. grid.x = B*Cout, block = 128 (t)
__global__ void conv1d_k3(const float* __restrict__ in, const float* __restrict__ wt,
                          const float* __restrict__ bias, float* __restrict__ out,
                          int Cin_total, int Cin_g, int Cout, int ocpg) {
  int bo = blockIdx.x;
  int o = bo % Cout;
  int b = bo / Cout;
  int g = o / ocpg;
  int t = threadIdx.x;
  if (t >= 100) return;
  const float* ib = in + ((size_t)b * Cin_total + (size_t)g * Cin_g) * 100;
  const float* wr = wt + (size_t)o * Cin_g * 3;
  float acc = bias[o];
  for (int c = 0; c < Cin_g; ++c) {
    const float* row = ib + (size_t)c * 100;
    float w0 = wr[c * 3 + 0], w1 = wr[c * 3 + 1], w2 = wr[c * 3 + 2];
    float a = (t > 0) ? row[t - 1] : 0.f;
    float m = row[t];
    float z = (t < 99) ? row[t + 1] : 0.f;
    acc += w0 * a + w1 * m + w2 * z;
  }
  out[(size_t)bo * 100 + t] = fmaxf(acc, 0.f);
}

__global__ void head_sig(const float* __restrict__ mid, const float* __restrict__ w,
                         const float* __restrict__ bias, float* __restrict__ out) {
  int idx = blockIdx.x * blockDim.x + threadIdx.x;
  if (idx >= 200) return;
  int b = idx / 100, t = idx % 100;
  float acc = bias[0];
  for (int c = 0; c < 256; ++c)
    acc += mid[((size_t)b * 256 + c) * 100 + t] * w[c];
  out[idx] = 1.f / (1.f + expf(-acc));
}

// q[b,o,n,pos] = sum_c w3d[o,c,n] p[b,c,pos]. grid = 1024 (b*512+o), block 128
__global__ void qgemm_k(const float* __restrict__ p, const float* __restrict__ w3d,
                        float* __restrict__ q) {
  int bb = blockIdx.x;
  int b = bb >> 9, o = bb & 511;
  int pos = threadIdx.x;
  int pc = pos < 100 ? pos : 99;
  const float* pb = p + (size_t)b * 25600;
  const float* wr = w3d + (size_t)o * 8192;
  float acc[32];
#pragma unroll
  for (int j = 0; j < 32; ++j) acc[j] = 0.f;
  for (int c = 0; c < 256; ++c) {
    float v = pb[c * 100 + pc];
    const float* w = wr + c * 32;
#pragma unroll
    for (int j = 0; j < 32; ++j) acc[j] += v * w[j];
  }
  if (pos < 100) {
#pragma unroll
    for (int j = 0; j < 32; ++j)
      q[((size_t)(bb * 32 + j)) * 100 + pos] = acc[j];
  }
}

// fmap[b,o,d,s] = relu(b3d[o] + valid(d,s)*interp(q)). grid=(1024,10), block 128
__global__ void fmap_k(const float* __restrict__ q, const int* __restrict__ tofs,
                       const float* __restrict__ tw0, const float* __restrict__ tw1,
                       const int* __restrict__ nbase, const int* __restrict__ nfl,
                       const float* __restrict__ nw0, const float* __restrict__ nw1,
                       const float* __restrict__ nwn, const int* __restrict__ npos,
                       const int* __restrict__ nneg, const float* __restrict__ b3d,
                       float* __restrict__ out) {
  __shared__ float qsp[32 * PADW];  // zero-padded rows: [n][0..99]=q, rest 0
  int bo = blockIdx.x;
  const float* qb = q + (size_t)bo * 3200;
  for (int idx = threadIdx.x; idx < 32 * PADW; idx += 128) qsp[idx] = 0.f;
  __syncthreads();
  for (int idx = threadIdx.x; idx < 3200; idx += 128) {
    int n = idx / 100;
    qsp[n * PADW + (idx - n * 100)] = qb[idx];
  }
  __syncthreads();
  float bias = b3d[bo & 511];
  int s = threadIdx.x;
  int sc = (s < 100) ? s : 99;
  for (int dd = 0; dd < 10; ++dd) {
    int d = blockIdx.y * 10 + dd;
    const int* to = tofs + d * 96;
    const float* t0 = tw0 + d * 96;
    const float* t1 = tw1 + d * 96;
    int np = npos[d];
    float a0 = 0.f, a1 = 0.f, a2 = 0.f, a3 = 0.f;
    for (int j = 0; j < np; j += 4) {
      int i0 = sc + to[j + 0];
      a0 += t0[j + 0] * qsp[i0];
      a1 += t1[j + 0] * qsp[i0 + 1];
      int i1 = sc + to[j + 1];
      a2 += t0[j + 1] * qsp[i1];
      a3 += t1[j + 1] * qsp[i1 + 1];
      int i2 = sc + to[j + 2];
      a0 += t0[j + 2] * qsp[i2];
      a1 += t1[j + 2] * qsp[i2 + 1];
      int i3 = sc + to[j + 3];
      a2 += t0[j + 3] * qsp[i3];
      a3 += t1[j + 3] * qsp[i3 + 1];
    }
    const int* nb = nbase + d * 64;
    const int* nf = nfl + d * 64;
    const float* m0 = nw0 + d * 64;
    const float* m1 = nw1 + d * 64;
    const float* mn = nwn + d * 64;
    int nq = nneg[d];
    for (int j = 0; j < nq; ++j) {
      int i = sc + nf[j];
      int ic = i > 0 ? i : 0;
      int ad = nb[j] + ic;
      float v0 = qsp[ad], v1 = qsp[ad + 1];
      float w0 = (i >= 0) ? m0[j] : ((i == -1) ? mn[j] : 0.f);
      float w1 = (i >= 0) ? m1[j] : 0.f;
      a0 += w0 * v0;
      a1 += w1 * v1;
    }
    float acc = (a0 + a1) + (a2 + a3);
    if (s < 100) {
      float pre = bias + ((s + d < 100) ? acc : 0.f);
      out[((size_t)bo * 100 + d) * 100 + s] = fmaxf(pre, 0.f);
    }
  }
}

// 1x1 conv 512->128 + relu, SGPR weights. grid=(200,4), block=128
__global__ void conv1x1_c1(const float* __restrict__ in, const float* __restrict__ wT,
                           const float* __restrict__ bias, float* __restrict__ out) {
  int bd = blockIdx.x;
  int y = bd % 100;
  int b = bd / 100;
  int oc0 = blockIdx.y * 32;
  int t = threadIdx.x;
  int tc = t < 100 ? t : 99;
  float acc[32];
#pragma unroll
  for (int j = 0; j < 32; ++j) acc[j] = 0.f;
  const float* inb = in + (size_t)b * 512 * 10000 + (size_t)y * 100 + tc;
  for (int c = 0; c < 512; ++c) {
    float v = inb[(size_t)c * 10000];
    const float* w = wT + c * 128 + oc0;
#pragma unroll
    for (int j = 0; j < 32; ++j) acc[j] += v * w[j];
  }
  if (t < 100) {
#pragma unroll
    for (int j = 0; j < 32; ++j)
      out[((size_t)(b * 128 + oc0 + j) * 100 + y) * 100 + t] =
          fmaxf(acc[j] + bias[oc0 + j], 0.f);
  }
}

// 3x3 conv 128->128 pad 1 + relu, SGPR weights. grid=(200,4), block=128
__global__ void conv3x3_c(const float* __restrict__ in, const float* __restrict__ wT,
                          const float* __restrict__ bias, float* __restrict__ out) {
  int bd = blockIdx.x;
  int y = bd % 100;
  int b = bd / 100;
  int oc0 = blockIdx.y * 32;
  int t = threadIdx.x;
  int tc = t < 100 ? t : 99;
  float acc[32];
#pragma unroll
  for (int j = 0; j < 32; ++j) acc[j] = 0.f;
  for (int c = 0; c < 128; ++c) {
    const float* ib = in + ((size_t)(b * 128 + c)) * 10000;
#pragma unroll
    for (int ky = 0; ky < 3; ++ky) {
      int yy = y + ky - 1;
      if ((unsigned)yy > 99u) continue;
      const float* row = ib + (size_t)yy * 100;
      float vm = (tc > 0) ? row[tc - 1] : 0.f;
      float v0 = row[tc];
      float vp = (tc < 99) ? row[tc + 1] : 0.f;
      const float* w = wT + ((size_t)(c * 3 + ky) * 3) * 128 + oc0;
#pragma unroll
      for (int j = 0; j < 32; ++j) acc[j] += vm * w[j];
#pragma unroll
      for (int j = 0; j < 32; ++j) acc[j] += v0 * w[128 + j];
#pragma unroll
      for (int j = 0; j < 32; ++j) acc[j] += vp * w[256 + j];
    }
  }
  if (t < 100) {
#pragma unroll
    for (int j = 0; j < 32; ++j)
      out[((size_t)(b * 128 + oc0 + j) * 100 + y) * 100 + t] =
          fmaxf(acc[j] + bias[oc0 + j], 0.f);
  }
}

// final 1x1 conv 128->2 + sigmoid -> conf
__global__ void conv1x1_final(const float* __restrict__ in, const float* __restrict__ w,
                              const float* __restrict__ bias, float* __restrict__ out) {
  int idx = blockIdx.x * blockDim.x + threadIdx.x;
  if (idx >= 40000) return;
  int sp = idx % 10000;
  int i = (idx / 10000) & 1;
  int b = idx / 20000;
  float acc = bias[i];
  const float* ib = in + (size_t)b * 128 * 10000 + sp;
#pragma unroll 4
  for (int c = 0; c < 128; ++c)
    acc += ib[(size_t)c * 10000] * w[i * 128 + c];
  out[idx] = 1.f / (1.f + expf(-acc));
}

extern "C" void kernel_launch(void* const* d_in, const int* in_sizes, int n_in,
                              void* d_out, int out_size, void* d_ws, size_t ws_size,
                              hipStream_t stream) {
  const float* x    = (const float*)d_in[0];
  const float* w_b1 = (const float*)d_in[1];
  const float* b_b1 = (const float*)d_in[2];
  const float* w_b2 = (const float*)d_in[3];
  const float* b_b2 = (const float*)d_in[4];
  const float* w_s1 = (const float*)d_in[5];
  const float* b_s1 = (const float*)d_in[6];
  const float* w_s2 = (const float*)d_in[7];
  const float* b_s2 = (const float*)d_in[8];
  const float* w_e1 = (const float*)d_in[9];
  const float* b_e1 = (const float*)d_in[10];
  const float* w_e2 = (const float*)d_in[11];
  const float* b_e2 = (const float*)d_in[12];
  const float* w_p  = (const float*)d_in[13];
  const float* b_p  = (const float*)d_in[14];
  const float* w_3d = (const float*)d_in[15];
  const float* b_3d = (const float*)d_in[16];
  const float* w_c1 = (const float*)d_in[17];
  const float* b_c1 = (const float*)d_in[18];
  const float* w_c2 = (const float*)d_in[19];
  const float* b_c2 = (const float*)d_in[20];
  const float* w_c3 = (const float*)d_in[21];
  const float* b_c3 = (const float*)d_in[22];
  const float* w_c4 = (const float*)d_in[23];
  const float* b_c4 = (const float*)d_in[24];
  // d_in[25] = sample_mask (unused: replaced by analytic table)

  float* out = (float*)d_out;
  float* ws  = (float*)d_ws;

  // workspace layout (float offsets)
  float* h1  = ws;                      // 51200
  float* h2  = ws + 51200;              // 51200
  float* mid = ws + 102400;             // 51200
  float* p   = ws + 153600;             // 51200
  float* wT1 = ws + 204800;             // 65536
  float* wT2 = ws + 270336;             // 147456
  float* wT3 = ws + 417792;             // 147456
  int*   tofs  = (int*)(ws + 565248);   // 9600
  float* tw0   = ws + 574848;           // 9600
  float* tw1   = ws + 584448;           // 9600
  int*   nbase = (int*)(ws + 594048);   // 6400
  int*   nfl   = (int*)(ws + 600448);   // 6400
  float* nw0   = ws + 606848;           // 6400
  float* nw1   = ws + 613248;           // 6400
  float* nwn   = ws + 619648;           // 6400
  int*   npos  = (int*)(ws + 626048);   // 128
  int*   nneg  = (int*)(ws + 626176);   // 128
  float* q   = ws + 626304;             // 3,276,800 (dead after fmap_k)
  float* c1b = ws + 626304;             // 2,560,000 (reuses q region)
  float* c2b = ws + 3186304;            // 2,560,000

  float* out_conf  = out;               // 40,000
  float* out_start = out + 40000;       // 200
  float* out_end   = out + 40200;       // 200
  float* out_fmap  = out + 40400;       // 10,240,000

  hipLaunchKernelGGL(build_table_k, dim3(1), dim3(128), 0, stream,
                     tofs, tw0, tw1, nbase, nfl, nw0, nw1, nwn, npos, nneg);
  hipLaunchKernelGGL(prep_w_k, dim3(576), dim3(256), 0, stream,
                     w_c1, w_c2, w_c3, wT1, wT2, wT3);

  hipLaunchKernelGGL(conv1d_k3, dim3(512), dim3(128), 0, stream,
                     x, w_b1, b_b1, h1, 400, 100, 256, 64);
  hipLaunchKernelGGL(conv1d_k3, dim3(512), dim3(128), 0, stream,
                     h1, w_b2, b_b2, h2, 256, 64, 256, 64);

  hipLaunchKernelGGL(conv1d_k3, dim3(512), dim3(128), 0, stream,
                     h2, w_s1, b_s1, mid, 256, 64, 256, 64);
  hipLaunchKernelGGL(head_sig, dim3(2), dim3(128), 0, stream,
                     mid, w_s2, b_s2, out_start);
  hipLaunchKernelGGL(conv1d_k3, dim3(512), dim3(128), 0, stream,
                     h2, w_e1, b_e1, mid, 256, 64, 256, 64);
  hipLaunchKernelGGL(head_sig, dim3(2), dim3(128), 0, stream,
                     mid, w_e2, b_e2, out_end);

  hipLaunchKernelGGL(conv1d_k3, dim3(512), dim3(128), 0, stream,
                     h2, w_p, b_p, p, 256, 256, 256, 256);

  hipLaunchKernelGGL(qgemm_k, dim3(1024), dim3(128), 0, stream, p, w_3d, q);

  hipLaunchKernelGGL(fmap_k, dim3(1024, 10), dim3(128), 0, stream,
                     q, tofs, tw0, tw1, nbase, nfl, nw0, nw1, nwn, npos, nneg,
                     b_3d, out_fmap);

  hipLaunchKernelGGL(conv1x1_c1, dim3(200, 4), dim3(128), 0, stream,
                     out_fmap, wT1, b_c1, c1b);
  hipLaunchKernelGGL(conv3x3_c, dim3(200, 4), dim3(128), 0, stream,
                     c1b, wT2, b_c2, c2b);
  hipLaunchKernelGGL(conv3x3_c, dim3(200, 4), dim3(128), 0, stream,
                     c2b, wT3, b_c3, c1b);
  hipLaunchKernelGGL(conv1x1_final, dim3(157), dim3(256), 0, stream,
                     c1b, w_c4, b_c4, out_conf);
}

// Round 3
// 1224.416 us; speedup vs baseline: 1.7302x; 1.2611x over previous
//
#include <hip/hip_runtime.h>
#include <math.h>

// ---------------------------------------------------------------------------
// BMN forward on MI355X. B=2, T=100, DM=100, NS=32, NSPB=3, FEAT=400,
// H1=256, H2=128, H3=512.
// fmap path: sample_mask is s-shift-invariant => per-d tap table (ofs,w0,w1).
// qsp rows are zero-padded BOTH sides (PADL=52 left, up to +199 right) so all
// taps run one uniform 2-FMA path; the sole trunc-vs-floor special case
// (samp in (-1,0) -> net 1.0 at pos 0) is a short merged per-d correction
// list applied with a lane predicate. Taps with fl>99 are dead for all s and
// dropped at build time. Tables live in LDS (round-2 lesson: global/scalar
// table loads in the chain stall at low occupancy).
// ---------------------------------------------------------------------------

#define PADW 252
#define PADL 52

// tab[d][96]: int4 {ofs(+PADL baked), w0 bits, w1 bits, 0}; np[d] (even).
// ctab[d][64]: int2 {addr | starg<<16, w bits}; ncor[d].
__global__ void build_table_k(int4* __restrict__ tab, int* __restrict__ npd,
                              int2* __restrict__ ctab, int* __restrict__ ncord) {
  int d = threadIdx.x;
  if (d >= 100) return;
  double center = (double)d + 1.0;
  double step = (2.0 * d + 1.0) / 95.0;
  double xmin0 = -center * 0.5;
  int pp = 0, qq = 0;
  int lastfl = 1000, lastn = -1;
  for (int k = 0; k < 96; ++k) {
    double off = xmin0 + (double)k * step;
    double fld = floor(off);
    int fl = (int)fld;
    double frd = off - fld;  // in [0,1)
    int n = k / 3;
    if (fl <= 99) {  // fl >= -51 always; fl>99 contributes 0 for all s
      int4 e;
      e.x = n * PADW + PADL + fl;
      e.y = __float_as_int((float)((1.0 - frd) / 3.0));
      e.z = __float_as_int((float)(frd / 3.0));
      e.w = 0;
      tab[d * 96 + pp] = e;
      ++pp;
    }
    if (fl < 0 && frd > 0.0) {
      // lane s=-1-fl has samp in (-1,0): net weight 1.0 at pos 0; fast path
      // already gave fr/3 -> correction (1-fr)/3 * q[n][0].
      float cw = (float)((1.0 - frd) / 3.0);
      int st = -1 - fl;  // in [0,50]
      if (qq > 0 && fl == lastfl && n == lastn) {
        int2 pe = ctab[d * 64 + qq - 1];
        pe.y = __float_as_int(__int_as_float(pe.y) + cw);
        ctab[d * 64 + qq - 1] = pe;
      } else if (qq < 64) {
        int2 e;
        e.x = (n * PADW + PADL) | (st << 16);
        e.y = __float_as_int(cw);
        ctab[d * 64 + qq] = e;
        ++qq;
        lastfl = fl;
        lastn = n;
      }
    }
  }
  if (pp & 1) {  // pad to even with zero-weight tap
    int4 z;
    z.x = 0; z.y = 0; z.z = 0; z.w = 0;
    tab[d * 96 + pp] = z;
    ++pp;
  }
  npd[d] = pp;
  ncord[d] = qq;
}

// transpose conv2d weights for broadcast access
__global__ void prep_w_k(const float* __restrict__ w_c1, const float* __restrict__ w_c2,
                         const float* __restrict__ w_c3, float* __restrict__ wT1,
                         float* __restrict__ wT2, float* __restrict__ wT3) {
  int idx = blockIdx.x * 256 + threadIdx.x;
  if (idx < 512 * 128) {
    int c = idx >> 7, oc = idx & 127;
    wT1[idx] = w_c1[oc * 512 + c];
  }
  if (idx < 128 * 9 * 128) {
    int oc = idx & 127;
    int r = idx >> 7;
    int c = r / 9, tap = r % 9;
    wT2[idx] = w_c2[(oc * 128 + c) * 9 + tap];
    wT3[idx] = w_c3[(oc * 128 + c) * 9 + tap];
  }
}

// generic k=3 pad=1 grouped conv1d + relu. grid.x = B*Cout, block = 128 (t)
__global__ void conv1d_k3(const float* __restrict__ in, const float* __restrict__ wt,
                          const float* __restrict__ bias, float* __restrict__ out,
                          int Cin_total, int Cin_g, int Cout, int ocpg) {
  int bo = blockIdx.x;
  int o = bo % Cout;
  int b = bo / Cout;
  int g = o / ocpg;
  int t = threadIdx.x;
  if (t >= 100) return;
  const float* ib = in + ((size_t)b * Cin_total + (size_t)g * Cin_g) * 100;
  const float* wr = wt + (size_t)o * Cin_g * 3;
  float acc = bias[o];
#pragma unroll 4
  for (int c = 0; c < Cin_g; ++c) {
    const float* row = ib + (size_t)c * 100;
    float w0 = wr[c * 3 + 0], w1 = wr[c * 3 + 1], w2 = wr[c * 3 + 2];
    float a = (t > 0) ? row[t - 1] : 0.f;
    float m = row[t];
    float z = (t < 99) ? row[t + 1] : 0.f;
    acc += w0 * a + w1 * m + w2 * z;
  }
  out[(size_t)bo * 100 + t] = fmaxf(acc, 0.f);
}

__global__ void head_sig(const float* __restrict__ mid, const float* __restrict__ w,
                         const float* __restrict__ bias, float* __restrict__ out) {
  int idx = blockIdx.x * blockDim.x + threadIdx.x;
  if (idx >= 200) return;
  int b = idx / 100, t = idx % 100;
  float acc = bias[0];
  for (int c = 0; c < 256; ++c)
    acc += mid[((size_t)b * 256 + c) * 100 + t] * w[c];
  out[idx] = 1.f / (1.f + expf(-acc));
}

// q[b,o,n,pos] = sum_c w3d[o,c,n] p[b,c,pos]. grid = 1024 (b*512+o), block 128
__global__ void qgemm_k(const float* __restrict__ p, const float* __restrict__ w3d,
                        float* __restrict__ q) {
  int bb = blockIdx.x;
  int b = bb >> 9, o = bb & 511;
  int pos = threadIdx.x;
  int pc = pos < 100 ? pos : 99;
  const float* pb = p + (size_t)b * 25600;
  const float* wr = w3d + (size_t)o * 8192;
  float acc[32];
#pragma unroll
  for (int j = 0; j < 32; ++j) acc[j] = 0.f;
  for (int c = 0; c < 256; ++c) {
    float v = pb[c * 100 + pc];
    const float* w = wr + c * 32;
#pragma unroll
    for (int j = 0; j < 32; ++j) acc[j] += v * w[j];
  }
  if (pos < 100) {
#pragma unroll
    for (int j = 0; j < 32; ++j)
      q[((size_t)(bb * 32 + j)) * 100 + pos] = acc[j];
  }
}

// fmap[b,o,d,s]. grid=(1024,5), block 512 = 4 groups x 128 lanes(s).
// Each block: stage padded q rows once, then 5 iters x 4 groups = 20 d's.
__global__ __launch_bounds__(512) void fmap_k(
    const float* __restrict__ q, const int4* __restrict__ tab,
    const int* __restrict__ npd, const int2* __restrict__ ctab,
    const int* __restrict__ ncord, const float* __restrict__ b3d,
    float* __restrict__ out) {
  __shared__ float qsp[32 * PADW];   // 32256 B
  __shared__ float4 tabl[4][96];     // 6144 B
  __shared__ int2 ctl[4][64];        // 2048 B
  int bo = blockIdx.x;
  const float* qb = q + (size_t)bo * 3200;
  for (int i = threadIdx.x; i < 32 * PADW; i += 512) qsp[i] = 0.f;
  __syncthreads();
  for (int i = threadIdx.x; i < 3200; i += 512) {
    int n = i / 100;
    qsp[n * PADW + PADL + (i - n * 100)] = qb[i];
  }
  int g = threadIdx.x >> 7;
  int s = threadIdx.x & 127;
  int sc = s < 100 ? s : 99;
  float bias = b3d[bo & 511];
  for (int it = 0; it < 5; ++it) {
    int d = blockIdx.y * 20 + g * 5 + it;
    __syncthreads();
    if (s < 96) tabl[g][s] = ((const float4*)tab)[d * 96 + s];
    if (s < 64) ctl[g][s] = ctab[d * 64 + s];
    __syncthreads();
    int np = npd[d];
    int nc = ncord[d];
    float a0 = 0.f, a1 = 0.f, a2 = 0.f, a3 = 0.f;
    for (int j = 0; j < np; j += 2) {
      float4 e0 = tabl[g][j];
      float4 e1 = tabl[g][j + 1];
      int i0 = __float_as_int(e0.x) + sc;
      int i1 = __float_as_int(e1.x) + sc;
      a0 += e0.y * qsp[i0];
      a1 += e0.z * qsp[i0 + 1];
      a2 += e1.y * qsp[i1];
      a3 += e1.z * qsp[i1 + 1];
    }
    for (int j = 0; j < nc; ++j) {
      int2 c = ctl[g][j];
      int addr = c.x & 0xFFFF;
      int st = c.x >> 16;
      float w = (s == st) ? __int_as_float(c.y) : 0.f;
      a0 += w * qsp[addr];
    }
    float acc = (a0 + a2) + (a1 + a3);
    if (s < 100) {
      float pre = bias + ((s + d < 100) ? acc : 0.f);
      out[((size_t)bo * 100 + d) * 100 + s] = fmaxf(pre, 0.f);
    }
  }
}

// 1x1 conv 512->128 + relu. grid=(200,4), block=128
__global__ void conv1x1_c1(const float* __restrict__ in, const float* __restrict__ wT,
                           const float* __restrict__ bias, float* __restrict__ out) {
  int bd = blockIdx.x;
  int y = bd % 100;
  int b = bd / 100;
  int oc0 = blockIdx.y * 32;
  int t = threadIdx.x;
  int tc = t < 100 ? t : 99;
  float acc[32];
#pragma unroll
  for (int j = 0; j < 32; ++j) acc[j] = 0.f;
  const float* inb = in + (size_t)b * 512 * 10000 + (size_t)y * 100 + tc;
  for (int c = 0; c < 512; ++c) {
    float v = inb[(size_t)c * 10000];
    const float* w = wT + c * 128 + oc0;
#pragma unroll
    for (int j = 0; j < 32; ++j) acc[j] += v * w[j];
  }
  if (t < 100) {
#pragma unroll
    for (int j = 0; j < 32; ++j)
      out[((size_t)(b * 128 + oc0 + j) * 100 + y) * 100 + t] =
          fmaxf(acc[j] + bias[oc0 + j], 0.f);
  }
}

// 3x3 conv 128->128 pad 1 + relu. grid=(200,4), block=128
__global__ void conv3x3_c(const float* __restrict__ in, const float* __restrict__ wT,
                          const float* __restrict__ bias, float* __restrict__ out) {
  int bd = blockIdx.x;
  int y = bd % 100;
  int b = bd / 100;
  int oc0 = blockIdx.y * 32;
  int t = threadIdx.x;
  int tc = t < 100 ? t : 99;
  float acc[32];
#pragma unroll
  for (int j = 0; j < 32; ++j) acc[j] = 0.f;
  for (int c = 0; c < 128; ++c) {
    const float* ib = in + ((size_t)(b * 128 + c)) * 10000;
#pragma unroll
    for (int ky = 0; ky < 3; ++ky) {
      int yy = y + ky - 1;
      if ((unsigned)yy > 99u) continue;
      const float* row = ib + (size_t)yy * 100;
      float vm = (tc > 0) ? row[tc - 1] : 0.f;
      float v0 = row[tc];
      float vp = (tc < 99) ? row[tc + 1] : 0.f;
      const float* w = wT + ((size_t)(c * 3 + ky) * 3) * 128 + oc0;
#pragma unroll
      for (int j = 0; j < 32; ++j) acc[j] += vm * w[j];
#pragma unroll
      for (int j = 0; j < 32; ++j) acc[j] += v0 * w[128 + j];
#pragma unroll
      for (int j = 0; j < 32; ++j) acc[j] += vp * w[256 + j];
    }
  }
  if (t < 100) {
#pragma unroll
    for (int j = 0; j < 32; ++j)
      out[((size_t)(b * 128 + oc0 + j) * 100 + y) * 100 + t] =
          fmaxf(acc[j] + bias[oc0 + j], 0.f);
  }
}

// final 1x1 conv 128->2 + sigmoid. grid=625, block=256 (64 sp x 4 c-groups)
__global__ void conv1x1_final(const float* __restrict__ in, const float* __restrict__ w,
                              const float* __restrict__ bias, float* __restrict__ out) {
  __shared__ float part[256];
  int tid = threadIdx.x;
  int spl = tid & 63, cg = tid >> 6;
  int idx = blockIdx.x * 64 + spl;
  bool ok = idx < 40000;
  int ic = ok ? idx : 0;
  int sp = ic % 10000;
  int i = (ic / 10000) & 1;
  int b = ic / 20000;
  const float* ib = in + (size_t)b * 1280000 + (size_t)cg * 320000 + sp;
  const float* wp = w + i * 128 + cg * 32;
  float acc = 0.f;
#pragma unroll 8
  for (int c = 0; c < 32; ++c)
    acc += ib[(size_t)c * 10000] * wp[c];
  part[tid] = acc;
  __syncthreads();
  if (cg == 0 && ok) {
    float a = part[spl] + part[64 + spl] + part[128 + spl] + part[192 + spl] + bias[i];
    out[idx] = 1.f / (1.f + expf(-a));
  }
}

extern "C" void kernel_launch(void* const* d_in, const int* in_sizes, int n_in,
                              void* d_out, int out_size, void* d_ws, size_t ws_size,
                              hipStream_t stream) {
  const float* x    = (const float*)d_in[0];
  const float* w_b1 = (const float*)d_in[1];
  const float* b_b1 = (const float*)d_in[2];
  const float* w_b2 = (const float*)d_in[3];
  const float* b_b2 = (const float*)d_in[4];
  const float* w_s1 = (const float*)d_in[5];
  const float* b_s1 = (const float*)d_in[6];
  const float* w_s2 = (const float*)d_in[7];
  const float* b_s2 = (const float*)d_in[8];
  const float* w_e1 = (const float*)d_in[9];
  const float* b_e1 = (const float*)d_in[10];
  const float* w_e2 = (const float*)d_in[11];
  const float* b_e2 = (const float*)d_in[12];
  const float* w_p  = (const float*)d_in[13];
  const float* b_p  = (const float*)d_in[14];
  const float* w_3d = (const float*)d_in[15];
  const float* b_3d = (const float*)d_in[16];
  const float* w_c1 = (const float*)d_in[17];
  const float* b_c1 = (const float*)d_in[18];
  const float* w_c2 = (const float*)d_in[19];
  const float* b_c2 = (const float*)d_in[20];
  const float* w_c3 = (const float*)d_in[21];
  const float* b_c3 = (const float*)d_in[22];
  const float* w_c4 = (const float*)d_in[23];
  const float* b_c4 = (const float*)d_in[24];
  // d_in[25] = sample_mask (unused: replaced by analytic table)

  float* out = (float*)d_out;
  float* ws  = (float*)d_ws;

  // workspace layout (float offsets)
  float* h1  = ws;                        // 51200
  float* h2  = ws + 51200;                // 51200
  float* mid = ws + 102400;               // 51200
  float* p   = ws + 153600;               // 51200
  int4*  tab   = (int4*)(ws + 204800);    // 9600 int4 = 38400
  int*   npd   = (int*)(ws + 243200);     // 128
  int2*  ctab  = (int2*)(ws + 243328);    // 6400 int2 = 12800
  int*   ncord = (int*)(ws + 256128);     // 128
  float* wT1 = ws + 256256;               // 65536
  float* wT2 = ws + 321792;               // 147456
  float* wT3 = ws + 469248;               // 147456
  float* q   = ws + 616704;               // 3,276,800 (dead after fmap_k)
  float* c1b = ws + 616704;               // 2,560,000 (reuses q)
  float* c2b = ws + 3176704;              // 2,560,000 (reuses q tail)

  float* out_conf  = out;                 // 40,000
  float* out_start = out + 40000;         // 200
  float* out_end   = out + 40200;         // 200
  float* out_fmap  = out + 40400;         // 10,240,000

  hipLaunchKernelGGL(build_table_k, dim3(1), dim3(128), 0, stream,
                     tab, npd, ctab, ncord);
  hipLaunchKernelGGL(prep_w_k, dim3(576), dim3(256), 0, stream,
                     w_c1, w_c2, w_c3, wT1, wT2, wT3);

  hipLaunchKernelGGL(conv1d_k3, dim3(512), dim3(128), 0, stream,
                     x, w_b1, b_b1, h1, 400, 100, 256, 64);
  hipLaunchKernelGGL(conv1d_k3, dim3(512), dim3(128), 0, stream,
                     h1, w_b2, b_b2, h2, 256, 64, 256, 64);

  hipLaunchKernelGGL(conv1d_k3, dim3(512), dim3(128), 0, stream,
                     h2, w_s1, b_s1, mid, 256, 64, 256, 64);
  hipLaunchKernelGGL(head_sig, dim3(2), dim3(128), 0, stream,
                     mid, w_s2, b_s2, out_start);
  hipLaunchKernelGGL(conv1d_k3, dim3(512), dim3(128), 0, stream,
                     h2, w_e1, b_e1, mid, 256, 64, 256, 64);
  hipLaunchKernelGGL(head_sig, dim3(2), dim3(128), 0, stream,
                     mid, w_e2, b_e2, out_end);

  hipLaunchKernelGGL(conv1d_k3, dim3(512), dim3(128), 0, stream,
                     h2, w_p, b_p, p, 256, 256, 256, 256);

  hipLaunchKernelGGL(qgemm_k, dim3(1024), dim3(128), 0, stream, p, w_3d, q);

  hipLaunchKernelGGL(fmap_k, dim3(1024, 5), dim3(512), 0, stream,
                     q, tab, npd, ctab, ncord, b_3d, out_fmap);

  hipLaunchKernelGGL(conv1x1_c1, dim3(200, 4), dim3(128), 0, stream,
                     out_fmap, wT1, b_c1, c1b);
  hipLaunchKernelGGL(conv3x3_c, dim3(200, 4), dim3(128), 0, stream,
                     c1b, wT2, b_c2, c2b);
  hipLaunchKernelGGL(conv3x3_c, dim3(200, 4), dim3(128), 0, stream,
                     c2b, wT3, b_c3, c1b);
  hipLaunchKernelGGL(conv1x1_final, dim3(625), dim3(256), 0, stream,
                     c1b, w_c4, b_c4, out_conf);
}

// Round 4
// 995.764 us; speedup vs baseline: 2.1275x; 1.2296x over previous
//
#include <hip/hip_runtime.h>
#include <math.h>

// ---------------------------------------------------------------------------
// BMN forward on MI355X. B=2, T=100, DM=100, NS=32, NSPB=3, FEAT=400,
// H1=256, H2=128, H3=512.
// fmap path: sample_mask is s-shift-invariant => per-d tap table (ofs,w0,w1).
// qsp rows zero-padded BOTH sides (PADL=52, width 252) so all taps run one
// uniform 2-FMA path; the trunc-vs-floor special case (samp in (-1,0) ->
// net 1.0 at pos 0) is a short merged per-d correction list.
// Round-4: tables are read via the SCALAR pipe (readfirstlane-forced s_load)
// -- round-3 counters showed the LDS issue pipe saturated by broadcast
// table reads (VALUBusy 41%).
// ---------------------------------------------------------------------------

#define PADW 252
#define PADL 52

// tab[d][96]: int4 {ofs(+PADL baked), w0 bits, w1 bits, 0}; npd[d] (even).
// ctab[d][64]: int2 {addr | starg<<16, w bits}; ncord[d].
__global__ void build_table_k(int4* __restrict__ tab, int* __restrict__ npd,
                              int2* __restrict__ ctab, int* __restrict__ ncord) {
  int d = threadIdx.x;
  if (d >= 100) return;
  double center = (double)d + 1.0;
  double step = (2.0 * d + 1.0) / 95.0;
  double xmin0 = -center * 0.5;
  int pp = 0, qq = 0;
  int lastfl = 1000, lastn = -1;
  for (int k = 0; k < 96; ++k) {
    double off = xmin0 + (double)k * step;
    double fld = floor(off);
    int fl = (int)fld;
    double frd = off - fld;  // in [0,1)
    int n = k / 3;
    if (fl <= 99) {  // fl >= -51 always; fl>99 contributes 0 for all s
      int4 e;
      e.x = n * PADW + PADL + fl;
      e.y = __float_as_int((float)((1.0 - frd) / 3.0));
      e.z = __float_as_int((float)(frd / 3.0));
      e.w = 0;
      tab[d * 96 + pp] = e;
      ++pp;
    }
    if (fl < 0 && frd > 0.0) {
      // lane s=-1-fl has samp in (-1,0): net weight 1.0 at pos 0; fast path
      // already gave fr/3 -> correction (1-fr)/3 * q[n][0].
      float cw = (float)((1.0 - frd) / 3.0);
      int st = -1 - fl;  // in [0,50]
      if (qq > 0 && fl == lastfl && n == lastn) {
        int2 pe = ctab[d * 64 + qq - 1];
        pe.y = __float_as_int(__int_as_float(pe.y) + cw);
        ctab[d * 64 + qq - 1] = pe;
      } else if (qq < 64) {
        int2 e;
        e.x = (n * PADW + PADL) | (st << 16);
        e.y = __float_as_int(cw);
        ctab[d * 64 + qq] = e;
        ++qq;
        lastfl = fl;
        lastn = n;
      }
    }
  }
  if (pp & 1) {  // pad to even with zero-weight tap
    int4 z;
    z.x = 0; z.y = 0; z.z = 0; z.w = 0;
    tab[d * 96 + pp] = z;
    ++pp;
  }
  npd[d] = pp;
  ncord[d] = qq;
}

// transpose conv2d weights for broadcast access
__global__ void prep_w_k(const float* __restrict__ w_c1, const float* __restrict__ w_c2,
                         const float* __restrict__ w_c3, float* __restrict__ wT1,
                         float* __restrict__ wT2, float* __restrict__ wT3) {
  int idx = blockIdx.x * 256 + threadIdx.x;
  if (idx < 512 * 128) {
    int c = idx >> 7, oc = idx & 127;
    wT1[idx] = w_c1[oc * 512 + c];
  }
  if (idx < 128 * 9 * 128) {
    int oc = idx & 127;
    int r = idx >> 7;
    int c = r / 9, tap = r % 9;
    wT2[idx] = w_c2[(oc * 128 + c) * 9 + tap];
    wT3[idx] = w_c3[(oc * 128 + c) * 9 + tap];
  }
}

// k=3 pad=1 grouped conv1d + relu, 4-way channel split.
// grid.x = B*Cout, block = 512 (4 cg x 128 t)
__global__ __launch_bounds__(512) void conv1d_k3s(
    const float* __restrict__ in, const float* __restrict__ wt,
    const float* __restrict__ bias, float* __restrict__ out,
    int Cin_total, int Cin_g, int Cout, int ocpg) {
  __shared__ float part[512];
  int bo = blockIdx.x;
  int o = bo % Cout, b = bo / Cout, g = o / ocpg;
  int tid = threadIdx.x;
  int cg = __builtin_amdgcn_readfirstlane(tid >> 7);  // wave-uniform
  int t = tid & 127;
  int tc = t < 100 ? t : 99;
  int cpc = Cin_g >> 2;
  const float* ib = in + ((size_t)b * Cin_total + (size_t)g * Cin_g + (size_t)cg * cpc) * 100;
  const float* wr = wt + ((size_t)o * Cin_g + (size_t)cg * cpc) * 3;
  float acc = 0.f;
#pragma unroll 4
  for (int c = 0; c < cpc; ++c) {
    const float* row = ib + c * 100;
    float w0 = wr[c * 3 + 0], w1 = wr[c * 3 + 1], w2 = wr[c * 3 + 2];
    float a = (tc > 0) ? row[tc - 1] : 0.f;
    float m = row[tc];
    float z = (tc < 99) ? row[tc + 1] : 0.f;
    acc += w0 * a + w1 * m + w2 * z;
  }
  part[tid] = acc;
  __syncthreads();
  if (cg == 0 && t < 100) {
    float a = part[t] + part[128 + t] + part[256 + t] + part[384 + t] + bias[o];
    out[(size_t)bo * 100 + t] = fmaxf(a, 0.f);
  }
}

// 1x1 conv to 1 channel + sigmoid. grid=200 (one output), block=64
__global__ void head_sig(const float* __restrict__ mid, const float* __restrict__ w,
                         const float* __restrict__ bias, float* __restrict__ out) {
  int idx = blockIdx.x;
  int b = idx / 100, t = idx % 100;
  int l = threadIdx.x;
  float acc = 0.f;
#pragma unroll
  for (int c0 = 0; c0 < 256; c0 += 64)
    acc += mid[((size_t)b * 256 + c0 + l) * 100 + t] * w[c0 + l];
#pragma unroll
  for (int off = 32; off; off >>= 1) acc += __shfl_down(acc, off);
  if (l == 0) out[idx] = 1.f / (1.f + expf(-(acc + bias[0])));
}

// q[b,o,n,pos] = sum_c w3d[o,c,n] p[b,c,pos]. grid = 1024 (b*512+o), block 128
__global__ void qgemm_k(const float* __restrict__ p, const float* __restrict__ w3d,
                        float* __restrict__ q) {
  int bb = blockIdx.x;
  int b = bb >> 9, o = bb & 511;
  int pos = threadIdx.x;
  int pc = pos < 100 ? pos : 99;
  const float* pb = p + (size_t)b * 25600;
  const float* wr = w3d + (size_t)o * 8192;
  float acc[32];
#pragma unroll
  for (int j = 0; j < 32; ++j) acc[j] = 0.f;
  for (int c = 0; c < 256; ++c) {
    float v = pb[c * 100 + pc];
    const float* w = wr + c * 32;
#pragma unroll
    for (int j = 0; j < 32; ++j) acc[j] += v * w[j];
  }
  if (pos < 100) {
#pragma unroll
    for (int j = 0; j < 32; ++j)
      q[((size_t)(bb * 32 + j)) * 100 + pos] = acc[j];
  }
}

// fmap[b,o,d,s]. grid=(1024,5), block 512 = 4 groups x 128 lanes(s).
// Tables via scalar pipe; qsp gather is the only LDS traffic.
__global__ __launch_bounds__(512) void fmap_k(
    const float* __restrict__ q, const int4* __restrict__ tab,
    const int* __restrict__ npd, const int2* __restrict__ ctab,
    const int* __restrict__ ncord, const float* __restrict__ b3d,
    float* __restrict__ out) {
  __shared__ float qsp[32 * PADW];  // 32256 B
  int bo = blockIdx.x;
  const float* qb = q + (size_t)bo * 3200;
  for (int i = threadIdx.x; i < 32 * PADW; i += 512) qsp[i] = 0.f;
  __syncthreads();
  for (int i = threadIdx.x; i < 3200; i += 512) {
    int n = i / 100;
    qsp[n * PADW + PADL + (i - n * 100)] = qb[i];
  }
  __syncthreads();
  int g = threadIdx.x >> 7;
  int s = threadIdx.x & 127;
  int sc = s < 100 ? s : 99;
  float bias = b3d[bo & 511];
  for (int it = 0; it < 5; ++it) {
    int d = __builtin_amdgcn_readfirstlane(blockIdx.y * 20 + g * 5 + it);
    const int4* td = tab + d * 96;
    const int2* cd = ctab + d * 64;
    int np = npd[d];
    int nc = ncord[d];
    float a0 = 0.f, a1 = 0.f, a2 = 0.f, a3 = 0.f;
    for (int j = 0; j < np; j += 2) {
      int4 e0 = td[j];      // s_load (uniform addr): offsets+weights in SGPRs
      int4 e1 = td[j + 1];
      int i0 = e0.x + sc;
      int i1 = e1.x + sc;
      a0 += __int_as_float(e0.y) * qsp[i0];
      a1 += __int_as_float(e0.z) * qsp[i0 + 1];
      a2 += __int_as_float(e1.y) * qsp[i1];
      a3 += __int_as_float(e1.z) * qsp[i1 + 1];
    }
    for (int j = 0; j < nc; ++j) {
      int2 c = cd[j];       // s_load
      int addr = c.x & 0xFFFF;
      int st = c.x >> 16;
      float w = (s == st) ? __int_as_float(c.y) : 0.f;
      a0 += w * qsp[addr];
    }
    float acc = (a0 + a2) + (a1 + a3);
    if (s < 100) {
      float pre = bias + ((s + d < 100) ? acc : 0.f);
      out[((size_t)bo * 100 + d) * 100 + s] = fmaxf(pre, 0.f);
    }
  }
}

// 1x1 conv 512->128 + relu. grid=(200,4), block=128
__global__ void conv1x1_c1(const float* __restrict__ in, const float* __restrict__ wT,
                           const float* __restrict__ bias, float* __restrict__ out) {
  int bd = blockIdx.x;
  int y = bd % 100;
  int b = bd / 100;
  int oc0 = blockIdx.y * 32;
  int t = threadIdx.x;
  int tc = t < 100 ? t : 99;
  float acc[32];
#pragma unroll
  for (int j = 0; j < 32; ++j) acc[j] = 0.f;
  const float* inb = in + (size_t)b * 512 * 10000 + (size_t)y * 100 + tc;
  for (int c = 0; c < 512; ++c) {
    float v = inb[(size_t)c * 10000];
    const float* w = wT + c * 128 + oc0;
#pragma unroll
    for (int j = 0; j < 32; ++j) acc[j] += v * w[j];
  }
  if (t < 100) {
#pragma unroll
    for (int j = 0; j < 32; ++j)
      out[((size_t)(b * 128 + oc0 + j) * 100 + y) * 100 + t] =
          fmaxf(acc[j] + bias[oc0 + j], 0.f);
  }
}

// 3x3 conv 128->128 pad 1 + relu. grid=(200,4), block=128
__global__ void conv3x3_c(const float* __restrict__ in, const float* __restrict__ wT,
                          const float* __restrict__ bias, float* __restrict__ out) {
  int bd = blockIdx.x;
  int y = bd % 100;
  int b = bd / 100;
  int oc0 = blockIdx.y * 32;
  int t = threadIdx.x;
  int tc = t < 100 ? t : 99;
  float acc[32];
#pragma unroll
  for (int j = 0; j < 32; ++j) acc[j] = 0.f;
  for (int c = 0; c < 128; ++c) {
    const float* ib = in + ((size_t)(b * 128 + c)) * 10000;
#pragma unroll
    for (int ky = 0; ky < 3; ++ky) {
      int yy = y + ky - 1;
      if ((unsigned)yy > 99u) continue;
      const float* row = ib + (size_t)yy * 100;
      float vm = (tc > 0) ? row[tc - 1] : 0.f;
      float v0 = row[tc];
      float vp = (tc < 99) ? row[tc + 1] : 0.f;
      const float* w = wT + ((size_t)(c * 3 + ky) * 3) * 128 + oc0;
#pragma unroll
      for (int j = 0; j < 32; ++j) acc[j] += vm * w[j];
#pragma unroll
      for (int j = 0; j < 32; ++j) acc[j] += v0 * w[128 + j];
#pragma unroll
      for (int j = 0; j < 32; ++j) acc[j] += vp * w[256 + j];
    }
  }
  if (t < 100) {
#pragma unroll
    for (int j = 0; j < 32; ++j)
      out[((size_t)(b * 128 + oc0 + j) * 100 + y) * 100 + t] =
          fmaxf(acc[j] + bias[oc0 + j], 0.f);
  }
}

// final 1x1 conv 128->2 + sigmoid. grid=625, block=256 (64 sp x 4 c-groups)
__global__ void conv1x1_final(const float* __restrict__ in, const float* __restrict__ w,
                              const float* __restrict__ bias, float* __restrict__ out) {
  __shared__ float part[256];
  int tid = threadIdx.x;
  int spl = tid & 63, cg = tid >> 6;
  int idx = blockIdx.x * 64 + spl;
  bool ok = idx < 40000;
  int ic = ok ? idx : 0;
  int sp = ic % 10000;
  int i = (ic / 10000) & 1;
  int b = ic / 20000;
  const float* ib = in + (size_t)b * 1280000 + (size_t)cg * 320000 + sp;
  const float* wp = w + i * 128 + cg * 32;
  float acc = 0.f;
#pragma unroll 8
  for (int c = 0; c < 32; ++c)
    acc += ib[(size_t)c * 10000] * wp[c];
  part[tid] = acc;
  __syncthreads();
  if (cg == 0 && ok) {
    float a = part[spl] + part[64 + spl] + part[128 + spl] + part[192 + spl] + bias[i];
    out[idx] = 1.f / (1.f + expf(-a));
  }
}

extern "C" void kernel_launch(void* const* d_in, const int* in_sizes, int n_in,
                              void* d_out, int out_size, void* d_ws, size_t ws_size,
                              hipStream_t stream) {
  const float* x    = (const float*)d_in[0];
  const float* w_b1 = (const float*)d_in[1];
  const float* b_b1 = (const float*)d_in[2];
  const float* w_b2 = (const float*)d_in[3];
  const float* b_b2 = (const float*)d_in[4];
  const float* w_s1 = (const float*)d_in[5];
  const float* b_s1 = (const float*)d_in[6];
  const float* w_s2 = (const float*)d_in[7];
  const float* b_s2 = (const float*)d_in[8];
  const float* w_e1 = (const float*)d_in[9];
  const float* b_e1 = (const float*)d_in[10];
  const float* w_e2 = (const float*)d_in[11];
  const float* b_e2 = (const float*)d_in[12];
  const float* w_p  = (const float*)d_in[13];
  const float* b_p  = (const float*)d_in[14];
  const float* w_3d = (const float*)d_in[15];
  const float* b_3d = (const float*)d_in[16];
  const float* w_c1 = (const float*)d_in[17];
  const float* b_c1 = (const float*)d_in[18];
  const float* w_c2 = (const float*)d_in[19];
  const float* b_c2 = (const float*)d_in[20];
  const float* w_c3 = (const float*)d_in[21];
  const float* b_c3 = (const float*)d_in[22];
  const float* w_c4 = (const float*)d_in[23];
  const float* b_c4 = (const float*)d_in[24];
  // d_in[25] = sample_mask (unused: replaced by analytic table)

  float* out = (float*)d_out;
  float* ws  = (float*)d_ws;

  // workspace layout (float offsets)
  float* h1  = ws;                        // 51200
  float* h2  = ws + 51200;                // 51200
  float* mid = ws + 102400;               // 51200
  float* p   = ws + 153600;               // 51200
  int4*  tab   = (int4*)(ws + 204800);    // 9600 int4 = 38400
  int*   npd   = (int*)(ws + 243200);     // 128
  int2*  ctab  = (int2*)(ws + 243328);    // 6400 int2 = 12800
  int*   ncord = (int*)(ws + 256128);     // 128
  float* wT1 = ws + 256256;               // 65536
  float* wT2 = ws + 321792;               // 147456
  float* wT3 = ws + 469248;               // 147456
  float* q   = ws + 616704;               // 3,276,800 (dead after fmap_k)
  float* c1b = ws + 616704;               // 2,560,000 (reuses q)
  float* c2b = ws + 3176704;              // 2,560,000 (reuses q tail)

  float* out_conf  = out;                 // 40,000
  float* out_start = out + 40000;         // 200
  float* out_end   = out + 40200;         // 200
  float* out_fmap  = out + 40400;         // 10,240,000

  hipLaunchKernelGGL(build_table_k, dim3(1), dim3(128), 0, stream,
                     tab, npd, ctab, ncord);
  hipLaunchKernelGGL(prep_w_k, dim3(576), dim3(256), 0, stream,
                     w_c1, w_c2, w_c3, wT1, wT2, wT3);

  hipLaunchKernelGGL(conv1d_k3s, dim3(512), dim3(512), 0, stream,
                     x, w_b1, b_b1, h1, 400, 100, 256, 64);
  hipLaunchKernelGGL(conv1d_k3s, dim3(512), dim3(512), 0, stream,
                     h1, w_b2, b_b2, h2, 256, 64, 256, 64);

  hipLaunchKernelGGL(conv1d_k3s, dim3(512), dim3(512), 0, stream,
                     h2, w_s1, b_s1, mid, 256, 64, 256, 64);
  hipLaunchKernelGGL(head_sig, dim3(200), dim3(64), 0, stream,
                     mid, w_s2, b_s2, out_start);
  hipLaunchKernelGGL(conv1d_k3s, dim3(512), dim3(512), 0, stream,
                     h2, w_e1, b_e1, mid, 256, 64, 256, 64);
  hipLaunchKernelGGL(head_sig, dim3(200), dim3(64), 0, stream,
                     mid, w_e2, b_e2, out_end);

  hipLaunchKernelGGL(conv1d_k3s, dim3(512), dim3(512), 0, stream,
                     h2, w_p, b_p, p, 256, 256, 256, 256);

  hipLaunchKernelGGL(qgemm_k, dim3(1024), dim3(128), 0, stream, p, w_3d, q);

  hipLaunchKernelGGL(fmap_k, dim3(1024, 5), dim3(512), 0, stream,
                     q, tab, npd, ctab, ncord, b_3d, out_fmap);

  hipLaunchKernelGGL(conv1x1_c1, dim3(200, 4), dim3(128), 0, stream,
                     out_fmap, wT1, b_c1, c1b);
  hipLaunchKernelGGL(conv3x3_c, dim3(200, 4), dim3(128), 0, stream,
                     c1b, wT2, b_c2, c2b);
  hipLaunchKernelGGL(conv3x3_c, dim3(200, 4), dim3(128), 0, stream,
                     c2b, wT3, b_c3, c1b);
  hipLaunchKernelGGL(conv1x1_final, dim3(625), dim3(256), 0, stream,
                     c1b, w_c4, b_c4, out_conf);
}